// Round 4
// baseline (24.225 us; speedup 1.0000x reference)
//
#include <hip/hip_runtime.h>

// SDA_3977139716505 — spiking self-attention block.
//
// Mathematical collapse: the final `out = lif(attn * v)` stage receives a
// strictly binary {0,1} input (product of two spike tensors). LIF membrane
// v_t = (v_{t-1} + x_t)/2, v_0 = 0  =>  v_t <= 1 - 2^-t <= 0.9375 < V_TH = 1
// for T = 4, so it never spikes. Hence out == 0, conv3d(0, w) == 0, and
// bn(0, gamma, beta) == beta exactly in fp32.
//
// => output[t, b, c, n] = proj_beta[c].  Shape [4, 2, 128, 8, 32, 32]:
//    contiguous runs of N = 8192 floats per channel value. 33.55 MB writes.
//
// Perf: round-1 (1 float4/thread, 8192 wgs) hit 2.76 TB/s; fill ceiling on
// this chip is ~6.5 TB/s. This version: 2048 wgs, 4x16B nontemporal stores
// per thread. Uses ext_vector_type float4 (HIP_vector_type is rejected by
// __builtin_nontemporal_store).

typedef float f32x4 __attribute__((ext_vector_type(4)));

#define C_CH 128

__global__ __launch_bounds__(256) void beta_broadcast_kernel(
    const float* __restrict__ proj_beta,
    f32x4* __restrict__ out)
{
    // Each thread owns 4 consecutive float4s = 16 floats.
    // Slab per (t,b,c) = 2048 float4s; a 4-group never crosses a slab
    // boundary, so channel is constant across the thread's stores.
    int g = blockIdx.x * blockDim.x + threadIdx.x;   // 524288 threads
    int base = g << 2;                               // first float4 index
    int c = (base >> 11) & (C_CH - 1);               // channel
    float b = proj_beta[c];
    f32x4 v = { b, b, b, b };
    __builtin_nontemporal_store(v, &out[base + 0]);
    __builtin_nontemporal_store(v, &out[base + 1]);
    __builtin_nontemporal_store(v, &out[base + 2]);
    __builtin_nontemporal_store(v, &out[base + 3]);
}

extern "C" void kernel_launch(void* const* d_in, const int* in_sizes, int n_in,
                              void* d_out, int out_size, void* d_ws, size_t ws_size,
                              hipStream_t stream) {
    // input order: ... 11: proj_beta
    const float* proj_beta = (const float*)d_in[11];

    const int total4 = out_size / 4;       // 2,097,152 float4 stores
    const int groups = total4 / 4;         // 524,288 threads
    const int block = 256;
    const int grid = groups / block;       // 2048 workgroups

    beta_broadcast_kernel<<<grid, block, 0, stream>>>(
        proj_beta, (f32x4*)d_out);
}

// Round 5
// 12.073 us; speedup vs baseline: 2.0065x; 2.0065x over previous
//
#include <hip/hip_runtime.h>

// SDA_3977139716505 — spiking self-attention block.
//
// Mathematical collapse: the final `out = lif(attn * v)` stage receives a
// strictly binary {0,1} input (product of two spike tensors). LIF membrane
// v_t = (v_{t-1} + x_t)/2, v_0 = 0  =>  v_t <= 1 - 2^-t <= 0.9375 < V_TH = 1
// for T = 4, so it never spikes. Hence out == 0, conv3d(0, w) == 0, and
// bn(0, gamma, beta) == beta exactly in fp32.
//
// => output[t, b, c, n] = proj_beta[c].  Shape [4, 2, 128, 8, 32, 32]:
//    contiguous runs of N = 8192 floats per channel. 33.55 MB pure writes.
//
// Perf history:
//   R1: 1 float4/thread, lane-contiguous, 8192 wgs        -> 12.16 us
//   R4: 4 thread-local float4s + nontemporal (stride-64B
//       lanes = UNCOALESCED writes)                        -> 24.2 us  (2x loss)
//   R5 (this): block-strided stores — every wave-store is 64 lanes x 16 B
//       contiguous (4 KB dense), 4-way ILP/thread, block-uniform channel
//       (scalar beta load), no nontemporal.

typedef float f32x4 __attribute__((ext_vector_type(4)));

#define C_CH 128

__global__ __launch_bounds__(256) void beta_broadcast_kernel(
    const float* __restrict__ proj_beta,
    f32x4* __restrict__ out)
{
    // Block b owns float4 range [b*1024, b*1024 + 1024).
    // Slab (one t,b,c) = 2048 float4s, so slab index = b >> 1: block-uniform.
    int c = (blockIdx.x >> 1) & (C_CH - 1);
    float bv = proj_beta[c];                 // scalar (uniform) load
    f32x4 v = { bv, bv, bv, bv };

    int base = (blockIdx.x << 10) + threadIdx.x;  // float4 index of store 0
    // 4 wave-coalesced stores, each 256 threads * 16 B contiguous.
    out[base +   0] = v;
    out[base + 256] = v;
    out[base + 512] = v;
    out[base + 768] = v;
}

extern "C" void kernel_launch(void* const* d_in, const int* in_sizes, int n_in,
                              void* d_out, int out_size, void* d_ws, size_t ws_size,
                              hipStream_t stream) {
    // input order: ... 11: proj_beta
    const float* proj_beta = (const float*)d_in[11];

    const int total4 = out_size / 4;       // 2,097,152 float4 stores
    const int block = 256;
    const int grid = total4 / (block * 4); // 2048 workgroups, 1024 float4s each

    beta_broadcast_kernel<<<grid, block, 0, stream>>>(
        proj_beta, (f32x4*)d_out);
}